// Round 4
// baseline (157.469 us; speedup 1.0000x reference)
//
#include <hip/hip_runtime.h>
#include <hip/hip_bf16.h>

#define NR 8192
#define DIM 512

typedef __attribute__((ext_vector_type(8))) short bf16x8;
typedef __attribute__((ext_vector_type(16))) float f32x16;
typedef __attribute__((ext_vector_type(4))) float f32x4;

__device__ static inline void gload_lds16(const void* g, void* l) {
    __builtin_amdgcn_global_load_lds(
        (const __attribute__((address_space(1))) void*)g,
        (__attribute__((address_space(3))) void*)l, 16, 0, 0);
}

// One block (256 threads) per row: compute |im|^2, |s|^2, im.s in one pass,
// write bf16-normalized rows + fp32 diag. Block 0 also zeroes the accumulator.
__global__ __launch_bounds__(256) void normalize_kernel(
    const float* __restrict__ im, const float* __restrict__ s,
    __hip_bfloat16* __restrict__ im_n, __hip_bfloat16* __restrict__ s_n,
    float* __restrict__ diag, double* __restrict__ acc)
{
    const int row = blockIdx.x;
    const int t = threadIdx.x;
    if (row == 0 && t == 0) acc[0] = 0.0;

    const float2* imr = (const float2*)(im + (size_t)row * DIM);
    const float2* sr  = (const float2*)(s  + (size_t)row * DIM);
    float2 iv = imr[t];
    float2 sv = sr[t];

    float sim = iv.x * iv.x + iv.y * iv.y;
    float sss = sv.x * sv.x + sv.y * sv.y;
    float sd  = iv.x * sv.x + iv.y * sv.y;

    #pragma unroll
    for (int off = 32; off; off >>= 1) {
        sim += __shfl_down(sim, off);
        sss += __shfl_down(sss, off);
        sd  += __shfl_down(sd, off);
    }

    __shared__ float red[3][4];
    const int wid = t >> 6, lane = t & 63;
    if (lane == 0) { red[0][wid] = sim; red[1][wid] = sss; red[2][wid] = sd; }
    __syncthreads();
    sim = red[0][0] + red[0][1] + red[0][2] + red[0][3];
    sss = red[1][0] + red[1][1] + red[1][2] + red[1][3];
    sd  = red[2][0] + red[2][1] + red[2][2] + red[2][3];

    const float ri = rsqrtf(sim);
    const float rs = rsqrtf(sss);
    if (t == 0) diag[row] = sd * ri * rs;

    __hip_bfloat162* io = (__hip_bfloat162*)(im_n + (size_t)row * DIM);
    __hip_bfloat162* so = (__hip_bfloat162*)(s_n  + (size_t)row * DIM);
    __hip_bfloat162 a, b;
    a.x = __float2bfloat16(iv.x * ri); a.y = __float2bfloat16(iv.y * ri);
    b.x = __float2bfloat16(sv.x * rs); b.y = __float2bfloat16(sv.y * rs);
    io[t] = a;
    so[t] = b;
}

// Persistent-block GEMM: grid=256 (1/CU), each block owns a 2x2 supertile of
// 256x256 output tiles (512x512). 32 K-tiles (BK=64) run as ONE continuous
// pipeline. LDS chunk-major [buf][chunk 0..7][row 0..255][16B] per matrix;
// phase ks reads chunk-pair {2ks,2ks+1} (6 x ds_read_b128, conflict-free) and
// issues 8 x mfma_32x32x16. Staging: 2 gload_lds16/thread/phase, chunk-pair p
// of K-tile g+1 staged during phase p of window g -> consumed 4 phases later;
// per-phase s_waitcnt vmcnt(6) drains only ~1800-cycle-old loads (no stall).
// Fused ranking-loss epilogue per output tile, running lsum, one atomicAdd.
__global__ __launch_bounds__(512, 2) void gemm_loss_kernel(
    const __hip_bfloat16* __restrict__ A,
    const __hip_bfloat16* __restrict__ B,
    const float* __restrict__ diag,
    double* __restrict__ acc_out)
{
    __shared__ char Asm[2][32768];   // [buf][c][row][16]
    __shared__ char Bsm[2][32768];
    __shared__ float part[8];

    const int tid = threadIdx.x;
    const int l   = tid & 63;
    const int w   = tid >> 6;         // wave 0..7
    const int wm  = w >> 2;           // 0..1 : M half (rows wm*128+)
    const int wn  = w & 3;            // 0..3 : N quarter (cols wn*64+)
    const int sbm = blockIdx.x >> 4;  // supertile row 0..15
    const int sbn = blockIdx.x & 15;  // supertile col 0..15

    // staging mapping: wave covers rows sr0..sr0+63 at chunk 2p+scw
    const int scw = w >> 2;           // 0/1: chunk within pair
    const int sr0 = (w & 3) * 64;     // row base
    const int hi  = l >> 5;           // lane half
    const int lc  = l & 31;           // lane row/col

    const char* Ab = (const char*)A;
    const char* Bb = (const char*)B;

    // stage chunk-pair p of K-tile g (g in 0..31) into buffer g&1
    auto stage_cp = [&](int g, int p) {
        const int t  = g >> 3;
        const int bm = sbm * 2 + (t >> 1);
        const int bn = sbn * 2 + (t & 1);
        const int kb = (g & 7) * 128;            // byte offset within row
        const int buf = g & 1;
        const int c   = 2 * p + scw;
        const int row = sr0 + l;
        gload_lds16(Ab + (size_t)(bm * 256 + row) * 1024 + kb + c * 16,
                    &Asm[buf][c * 4096 + sr0 * 16]);
        gload_lds16(Bb + (size_t)(bn * 256 + row) * 1024 + kb + c * 16,
                    &Bsm[buf][c * 4096 + sr0 * 16]);
    };

    bf16x8 af[4], bf2[2];
    auto ldfrags = [&](int buf, int ks) {
        const int cb = (2 * ks + hi) * 4096 + lc * 16;   // per-lane base
        #pragma unroll
        for (int mi = 0; mi < 4; ++mi)
            af[mi] = *(const bf16x8*)&Asm[buf][cb + (wm * 128 + mi * 32) * 16];
        #pragma unroll
        for (int ni = 0; ni < 2; ++ni)
            bf2[ni] = *(const bf16x8*)&Bsm[buf][cb + (wn * 64 + ni * 32) * 16];
    };

    f32x16 acc[4][2];
    f32x16 z16 = {0.f,0.f,0.f,0.f,0.f,0.f,0.f,0.f,0.f,0.f,0.f,0.f,0.f,0.f,0.f,0.f};
    #pragma unroll
    for (int mi = 0; mi < 4; ++mi)
        #pragma unroll
        for (int ni = 0; ni < 2; ++ni) acc[mi][ni] = z16;

    auto mmaph = [&]() {
        __builtin_amdgcn_s_setprio(1);
        #pragma unroll
        for (int mi = 0; mi < 4; ++mi)
            #pragma unroll
            for (int ni = 0; ni < 2; ++ni)
                acc[mi][ni] = __builtin_amdgcn_mfma_f32_32x32x16_bf16(
                    af[mi], bf2[ni], acc[mi][ni], 0, 0, 0);
        __builtin_amdgcn_s_setprio(0);
    };

    float lsum = 0.f;

    // fused loss epilogue for output tile t; C/D: col=lane&31,
    // row=(reg&3)+8*(reg>>2)+4*(lane>>5), reg = gq*4+rr
    auto epi = [&](int t) {
        const int bm = sbm * 2 + (t >> 1);
        const int bn = sbn * 2 + (t & 1);
        const int rb = bm * 256 + wm * 128;
        const int cbase = bn * 256 + wn * 64;
        float dc[2];
        dc[0] = diag[cbase + lc];
        dc[1] = diag[cbase + 32 + lc];
        #pragma unroll
        for (int mi = 0; mi < 4; ++mi) {
            #pragma unroll
            for (int gq = 0; gq < 4; ++gq) {
                const int r0 = rb + mi * 32 + gq * 8 + hi * 4;
                const f32x4 dr = *(const f32x4*)&diag[r0];
                #pragma unroll
                for (int ni = 0; ni < 2; ++ni) {
                    const int col = cbase + ni * 32 + lc;
                    #pragma unroll
                    for (int rr = 0; rr < 4; ++rr) {
                        if (r0 + rr != col) {
                            const float sc = acc[mi][ni][gq * 4 + rr];
                            lsum += fmaxf(0.f, 1.0f - dc[ni] + sc)
                                  + fmaxf(0.f, 1.0f - dr[rr] + sc);
                        }
                    }
                }
            }
        }
    };

    #define BAR __builtin_amdgcn_s_barrier()

    // ---- prologue: stage K-tile 0 (8 ops); drain cp0 ----
    #pragma unroll
    for (int p = 0; p < 4; ++p) stage_cp(0, p);
    asm volatile("s_waitcnt vmcnt(6)" ::: "memory");
    BAR;

    // ---- main pipeline: windows g=0..30 stage K-tile g+1 ----
    for (int g = 0; g < 31; ++g) {
        const int buf = g & 1;
        #pragma unroll
        for (int p = 0; p < 4; ++p) {
            ldfrags(buf, p);
            stage_cp(g + 1, p);
            asm volatile("s_waitcnt vmcnt(6)" ::: "memory");
            BAR;
            asm volatile("s_waitcnt lgkmcnt(0)" ::: "memory");
            mmaph();
            BAR;
        }
        if ((g & 7) == 7) {          // output-tile boundary (g = 7, 15, 23)
            epi(g >> 3);
            #pragma unroll
            for (int mi = 0; mi < 4; ++mi)
                #pragma unroll
                for (int ni = 0; ni < 2; ++ni) acc[mi][ni] = z16;
        }
    }

    // ---- last window g=31 (buf 1): no staging; drain 4 -> 2 -> 0 ----
    {
        ldfrags(1, 0);
        asm volatile("s_waitcnt vmcnt(4)" ::: "memory");
        BAR;
        asm volatile("s_waitcnt lgkmcnt(0)" ::: "memory");
        mmaph();
        BAR;
        ldfrags(1, 1);
        asm volatile("s_waitcnt vmcnt(2)" ::: "memory");
        BAR;
        asm volatile("s_waitcnt lgkmcnt(0)" ::: "memory");
        mmaph();
        BAR;
        ldfrags(1, 2);
        asm volatile("s_waitcnt vmcnt(0)" ::: "memory");
        BAR;
        asm volatile("s_waitcnt lgkmcnt(0)" ::: "memory");
        mmaph();
        BAR;
        ldfrags(1, 3);
        asm volatile("s_waitcnt lgkmcnt(0)" ::: "memory");
        mmaph();
    }
    epi(3);

    // ---- block reduction + single atomic ----
    #pragma unroll
    for (int off = 32; off; off >>= 1) lsum += __shfl_down(lsum, off);
    if (l == 0) part[w] = lsum;
    __syncthreads();
    if (tid == 0) {
        float bs = 0.f;
        #pragma unroll
        for (int i = 0; i < 8; ++i) bs += part[i];
        atomicAdd(acc_out, (double)bs);
    }
}

__global__ void finalize_kernel(const double* __restrict__ acc, float* __restrict__ out)
{
    out[0] = (float)(acc[0] * (1.0 / (double)NR));
}

extern "C" void kernel_launch(void* const* d_in, const int* in_sizes, int n_in,
                              void* d_out, int out_size, void* d_ws, size_t ws_size,
                              hipStream_t stream)
{
    const float* im = (const float*)d_in[0];
    const float* s  = (const float*)d_in[1];

    char* ws = (char*)d_ws;
    __hip_bfloat16* im_n = (__hip_bfloat16*)ws;                               // 8 MB
    __hip_bfloat16* s_n  = (__hip_bfloat16*)(ws + (size_t)NR * DIM * 2);      // 8 MB
    float* diag          = (float*)(ws + (size_t)NR * DIM * 4);               // 32 KB
    double* acc          = (double*)(ws + (size_t)NR * DIM * 4 + NR * 4);     // 8 B

    normalize_kernel<<<NR, 256, 0, stream>>>(im, s, im_n, s_n, diag, acc);

    gemm_loss_kernel<<<256, 512, 0, stream>>>(im_n, s_n, diag, acc);

    finalize_kernel<<<1, 1, 0, stream>>>(acc, (float*)d_out);
}

// Round 5
// 95.847 us; speedup vs baseline: 1.6429x; 1.6429x over previous
//
#include <hip/hip_runtime.h>
#include <hip/hip_bf16.h>

#define NR 8192
#define DIM 512

typedef __attribute__((ext_vector_type(8))) short bf16x8;
typedef __attribute__((ext_vector_type(16))) float f32x16;
typedef __attribute__((ext_vector_type(4))) float f32x4;

__device__ static inline void gload_lds16(const void* g, void* l) {
    __builtin_amdgcn_global_load_lds(
        (const __attribute__((address_space(1))) void*)g,
        (__attribute__((address_space(3))) void*)l, 16, 0, 0);
}

// One block (256 threads) per row: compute |im|^2, |s|^2, im.s in one pass,
// write bf16-normalized rows + fp32 diag. Block 0 also zeroes the accumulator.
__global__ __launch_bounds__(256) void normalize_kernel(
    const float* __restrict__ im, const float* __restrict__ s,
    __hip_bfloat16* __restrict__ im_n, __hip_bfloat16* __restrict__ s_n,
    float* __restrict__ diag, double* __restrict__ acc)
{
    const int row = blockIdx.x;
    const int t = threadIdx.x;
    if (row == 0 && t == 0) acc[0] = 0.0;

    const float2* imr = (const float2*)(im + (size_t)row * DIM);
    const float2* sr  = (const float2*)(s  + (size_t)row * DIM);
    float2 iv = imr[t];
    float2 sv = sr[t];

    float sim = iv.x * iv.x + iv.y * iv.y;
    float sss = sv.x * sv.x + sv.y * sv.y;
    float sd  = iv.x * sv.x + iv.y * sv.y;

    #pragma unroll
    for (int off = 32; off; off >>= 1) {
        sim += __shfl_down(sim, off);
        sss += __shfl_down(sss, off);
        sd  += __shfl_down(sd, off);
    }

    __shared__ float red[3][4];
    const int wid = t >> 6, lane = t & 63;
    if (lane == 0) { red[0][wid] = sim; red[1][wid] = sss; red[2][wid] = sd; }
    __syncthreads();
    sim = red[0][0] + red[0][1] + red[0][2] + red[0][3];
    sss = red[1][0] + red[1][1] + red[1][2] + red[1][3];
    sd  = red[2][0] + red[2][1] + red[2][2] + red[2][3];

    const float ri = rsqrtf(sim);
    const float rs = rsqrtf(sss);
    if (t == 0) diag[row] = sd * ri * rs;

    __hip_bfloat162* io = (__hip_bfloat162*)(im_n + (size_t)row * DIM);
    __hip_bfloat162* so = (__hip_bfloat162*)(s_n  + (size_t)row * DIM);
    __hip_bfloat162 a, b;
    a.x = __float2bfloat16(iv.x * ri); a.y = __float2bfloat16(iv.y * ri);
    b.x = __float2bfloat16(sv.x * rs); b.y = __float2bfloat16(sv.y * rs);
    io[t] = a;
    so[t] = b;
}

// Persistent-block GEMM: grid=256 (1/CU), block owns a 2x2 supertile of
// 256x256 tiles; 32 K-windows (BK=64) run as ONE continuous pipeline.
// LDS row-major [buf][row][128B] with XOR chunk swizzle (R3-verified),
// coalesced staging (R3-verified), 32x32x16 MFMA (R4-verified layouts).
// Slice-level software pipeline: ds_reads of k16-slice s+1 in flight under
// MFMA of slice s, gated by counted lgkmcnt(6); cross-window slice-0
// prefetch; stage tile g+2 during window g (vmcnt(0) drains ~1.5-window-old
// loads = free). Two barriers/window. diag cached in LDS; fused loss epi.
__global__ __launch_bounds__(512, 2) void gemm_loss_kernel(
    const __hip_bfloat16* __restrict__ A,
    const __hip_bfloat16* __restrict__ B,
    const float* __restrict__ diag,
    double* __restrict__ acc_out)
{
    __shared__ char Asm[2][32768];   // [buf][row 0..255][128B]
    __shared__ char Bsm[2][32768];
    __shared__ float dAr[512];       // diag rows of this supertile
    __shared__ float dBc[512];       // diag cols of this supertile
    __shared__ float part[8];

    const int tid = threadIdx.x;
    const int l   = tid & 63;
    const int w   = tid >> 6;         // wave 0..7
    const int wm  = w >> 2;           // 0..1 : rows wm*128..+127
    const int wn  = w & 3;            // 0..3 : cols wn*64..+63
    const int sbm = blockIdx.x >> 4;  // supertile row 0..15
    const int sbn = blockIdx.x & 15;  // supertile col 0..15

    const int lr = l >> 3;            // staging: row within 8-row group
    const int ls = l & 7;             // staging: 16B slot
    const int csw = ls ^ lr;          // pre-swizzled content chunk
    const int lc = l & 31;            // MFMA lane row/col
    const int hi = l >> 5;            // MFMA lane half

    const char* Ab = (const char*)A;
    const char* Bb = (const char*)B;

    // stage K-window gidx (tile (gidx>>3), k-idx (gidx&7)) into buf gidx&1
    auto stage = [&](int gidx) {
        const int tt = gidx >> 3, kk = gidx & 7;
        const int bmg = sbm * 2 + (tt >> 1);
        const int bng = sbn * 2 + (tt & 1);
        const int buf = gidx & 1;
        #pragma unroll
        for (int h = 0; h < 2; ++h)
            #pragma unroll
            for (int q = 0; q < 2; ++q) {
                const int rb = h * 128 + q * 64 + w * 8;
                gload_lds16(Ab + (size_t)(bmg * 256 + rb + lr) * 1024 + kk * 128 + csw * 16,
                            &Asm[buf][rb * 128]);
                gload_lds16(Bb + (size_t)(bng * 256 + rb + lr) * 1024 + kk * 128 + csw * 16,
                            &Bsm[buf][rb * 128]);
            }
    };

    // load fragments for k16-slice s (chunks 2s, 2s+1) from buf
    auto ldsl = [&](bf16x8 (&fa)[4], bf16x8 (&fb)[2], int buf, int s) {
        const int c = 2 * s + hi;
        #pragma unroll
        for (int mi = 0; mi < 4; ++mi) {
            const int row = wm * 128 + mi * 32 + lc;
            fa[mi] = *(const bf16x8*)&Asm[buf][row * 128 + ((c ^ (row & 7)) << 4)];
        }
        #pragma unroll
        for (int ni = 0; ni < 2; ++ni) {
            const int row = wn * 64 + ni * 32 + lc;
            fb[ni] = *(const bf16x8*)&Bsm[buf][row * 128 + ((c ^ (row & 7)) << 4)];
        }
    };

    f32x16 acc[4][2];
    f32x16 z16 = {0.f,0.f,0.f,0.f,0.f,0.f,0.f,0.f,0.f,0.f,0.f,0.f,0.f,0.f,0.f,0.f};
    #pragma unroll
    for (int mi = 0; mi < 4; ++mi)
        #pragma unroll
        for (int ni = 0; ni < 2; ++ni) acc[mi][ni] = z16;

    auto mmasl = [&](bf16x8 (&fa)[4], bf16x8 (&fb)[2]) {
        __builtin_amdgcn_s_setprio(1);
        #pragma unroll
        for (int mi = 0; mi < 4; ++mi)
            #pragma unroll
            for (int ni = 0; ni < 2; ++ni)
                acc[mi][ni] = __builtin_amdgcn_mfma_f32_32x32x16_bf16(
                    fa[mi], fb[ni], acc[mi][ni], 0, 0, 0);
        __builtin_amdgcn_s_setprio(0);
    };

    float lsum = 0.f;

    // fused loss epilogue for output tile t (0..3); diag from LDS
    auto epi = [&](int t) {
        const int rbl = (t >> 1) * 256 + wm * 128;
        const int cbl = (t & 1) * 256 + wn * 64;
        const float dc0 = dBc[cbl + lc];
        const float dc1 = dBc[cbl + 32 + lc];
        #pragma unroll
        for (int mi = 0; mi < 4; ++mi) {
            #pragma unroll
            for (int gq = 0; gq < 4; ++gq) {
                const int r0l = rbl + mi * 32 + gq * 8 + hi * 4;
                const f32x4 dr = *(const f32x4*)&dAr[r0l];
                const int r0g = sbm * 512 + r0l;
                #pragma unroll
                for (int ni = 0; ni < 2; ++ni) {
                    const int colg = sbn * 512 + cbl + ni * 32 + lc;
                    const float dcv = ni ? dc1 : dc0;
                    #pragma unroll
                    for (int rr = 0; rr < 4; ++rr) {
                        if (r0g + rr != colg) {
                            const float sc = acc[mi][ni][gq * 4 + rr];
                            lsum += fmaxf(0.f, 1.0f - dcv + sc)
                                  + fmaxf(0.f, 1.0f - dr[rr] + sc);
                        }
                    }
                }
            }
        }
        #pragma unroll
        for (int mi = 0; mi < 4; ++mi)
            #pragma unroll
            for (int ni = 0; ni < 2; ++ni) acc[mi][ni] = z16;
    };

    #define GATE6 do { asm volatile("s_waitcnt lgkmcnt(6)" ::: "memory"); \
                       __builtin_amdgcn_sched_barrier(0); } while (0)
    #define GATE0 do { asm volatile("s_waitcnt lgkmcnt(0)" ::: "memory"); \
                       __builtin_amdgcn_sched_barrier(0); } while (0)
    #define VM0   asm volatile("s_waitcnt vmcnt(0)" ::: "memory")
    #define BAR   __builtin_amdgcn_s_barrier()

    // ---- prologue: diag -> LDS, stage windows 0 and 1 ----
    dAr[tid] = diag[sbm * 512 + tid];
    dBc[tid] = diag[sbn * 512 + tid];
    __builtin_amdgcn_sched_barrier(0);
    stage(0); stage(1);
    asm volatile("s_waitcnt vmcnt(8) lgkmcnt(0)" ::: "memory");  // tile0 + diag done
    BAR;

    bf16x8 Sa_a[4], Sa_b[2], Sb_a[4], Sb_b[2];
    ldsl(Sa_a, Sa_b, 0, 0);   // prefetch (window 0, slice 0)

    // ---- main pipeline: windows g=0..29 (stage g+2) ----
    #pragma unroll 1
    for (int g = 0; g < 30; ++g) {
        const int buf = g & 1, nbuf = buf ^ 1;
        ldsl(Sb_a, Sb_b, buf, 1);  GATE6;  mmasl(Sa_a, Sa_b);   // slice 0
        ldsl(Sa_a, Sa_b, buf, 2);  GATE6;  mmasl(Sb_a, Sb_b);   // slice 1
        ldsl(Sb_a, Sb_b, buf, 3);  GATE6;  mmasl(Sa_a, Sa_b);   // slice 2
        VM0; BAR;                                               // tile g+1 visible
        ldsl(Sa_a, Sa_b, nbuf, 0);                              // prefetch (g+1, s0)
        GATE6;  mmasl(Sb_a, Sb_b);                              // slice 3
        BAR;                                                    // buf[g&1] free to overwrite
        if ((g & 7) == 7) { GATE0; epi(g >> 3); }               // tiles 0,1,2
        stage(g + 2);
    }

    // ---- window 30 (buf 0): no staging ----
    ldsl(Sb_a, Sb_b, 0, 1);  GATE6;  mmasl(Sa_a, Sa_b);
    ldsl(Sa_a, Sa_b, 0, 2);  GATE6;  mmasl(Sb_a, Sb_b);
    ldsl(Sb_a, Sb_b, 0, 3);  GATE6;  mmasl(Sa_a, Sa_b);
    VM0; BAR;                                                   // tile 31 visible
    ldsl(Sa_a, Sa_b, 1, 0);  GATE6;  mmasl(Sb_a, Sb_b);

    // ---- window 31 (buf 1) ----
    ldsl(Sb_a, Sb_b, 1, 1);  GATE6;  mmasl(Sa_a, Sa_b);
    ldsl(Sa_a, Sa_b, 1, 2);  GATE6;  mmasl(Sb_a, Sb_b);
    ldsl(Sb_a, Sb_b, 1, 3);  GATE6;  mmasl(Sa_a, Sa_b);
    GATE0;  mmasl(Sb_a, Sb_b);
    epi(3);

    // ---- block reduction + single atomic ----
    #pragma unroll
    for (int off = 32; off; off >>= 1) lsum += __shfl_down(lsum, off);
    if (l == 0) part[w] = lsum;
    __syncthreads();
    if (tid == 0) {
        float bs = 0.f;
        #pragma unroll
        for (int i = 0; i < 8; ++i) bs += part[i];
        atomicAdd(acc_out, (double)bs);
    }
}

__global__ void finalize_kernel(const double* __restrict__ acc, float* __restrict__ out)
{
    out[0] = (float)(acc[0] * (1.0 / (double)NR));
}

extern "C" void kernel_launch(void* const* d_in, const int* in_sizes, int n_in,
                              void* d_out, int out_size, void* d_ws, size_t ws_size,
                              hipStream_t stream)
{
    const float* im = (const float*)d_in[0];
    const float* s  = (const float*)d_in[1];

    char* ws = (char*)d_ws;
    __hip_bfloat16* im_n = (__hip_bfloat16*)ws;                               // 8 MB
    __hip_bfloat16* s_n  = (__hip_bfloat16*)(ws + (size_t)NR * DIM * 2);      // 8 MB
    float* diag          = (float*)(ws + (size_t)NR * DIM * 4);               // 32 KB
    double* acc          = (double*)(ws + (size_t)NR * DIM * 4 + NR * 4);     // 8 B

    normalize_kernel<<<NR, 256, 0, stream>>>(im, s, im_n, s_n, diag, acc);

    gemm_loss_kernel<<<256, 512, 0, stream>>>(im_n, s_n, diag, acc);

    finalize_kernel<<<1, 1, 0, stream>>>(acc, (float*)d_out);
}